// Round 3
// baseline (11504.697 us; speedup 1.0000x reference)
//
#include <hip/hip_runtime.h>
#include <hip/hip_bf16.h>
#include <math.h>

using bf16 = __hip_bfloat16;

__device__ __forceinline__ float b2f(bf16 v) { return __bfloat162float(v); }

// mode: 1 = inputs are bf16, 0 = inputs are float32.  (float)->exact, (bf16)->exact float.
__device__ __forceinline__ float ldv(const void* p, size_t i, int m) {
  return m ? b2f(((const bf16*)p)[i]) : ((const float*)p)[i];
}

struct Rec { int pix; float e2; };
#define FLAG_CAP 131072
#define MARGIN 1e-5f

// ---- f64 block reductions (blockDim == 256) ----
__device__ __forceinline__ void stats_reduce2d(double v, double v2, double* ga, double* gb) {
#pragma unroll
  for (int o = 32; o; o >>= 1) { v += __shfl_down(v, o, 64); v2 += __shfl_down(v2, o, 64); }
  __shared__ double l1[4], l2[4];
  int lane = threadIdx.x & 63, w = threadIdx.x >> 6;
  if (lane == 0) { l1[w] = v; l2[w] = v2; }
  __syncthreads();
  if (threadIdx.x == 0) {
    atomicAdd(ga, l1[0] + l1[1] + l1[2] + l1[3]);
    atomicAdd(gb, l2[0] + l2[1] + l2[2] + l2[3]);
  }
}

__device__ __forceinline__ void stats_reduce1d(double v, double* ga) {
#pragma unroll
  for (int o = 32; o; o >>= 1) v += __shfl_down(v, o, 64);
  __shared__ double l1[4];
  int lane = threadIdx.x & 63, w = threadIdx.x >> 6;
  if (lane == 0) l1[w] = v;
  __syncthreads();
  if (threadIdx.x == 0) atomicAdd(ga, l1[0] + l1[1] + l1[2] + l1[3]);
}

// ws layout:
//   STD (double, 512): per-BN block of 64 at l*64: [0:16) sum [16:32) sumsq
//        [32:48) scale(f64) [48:64) shift(f64).  [320] vq_sum  [321] recon_sum
//   STF (float, at +4096): per-BN block of 32 at l*32: [0:16) scale [16:32) shift
//   flagcnt (int, at +6144);  MODE (int, at +6148)
//   Rec flags[FLAG_CAP] at +8192 (1MB)
//   A (fp32 h1/d2) at +4MB; B (h2/d1) +4MB+128MB; C3 +4MB+160MB; D0 +4MB+162MB

// zero stats + detect input dtype (bf16 low-halfword of packed pair is in [0x3000,0x4000) for U[0,1])
__global__ void init_k(double* st, int* flagcnt, const unsigned* __restrict__ xw, int* flag) {
  st[threadIdx.x] = 0.0;
  st[256 + threadIdx.x] = 0.0;
  if (threadIdx.x == 0) *flagcnt = 0;
  unsigned lo = xw[threadIdx.x] & 0xFFFFu;
  int inr = (lo >= 0x3000u && lo < 0x4000u) ? 1 : 0;
  unsigned long long b = __ballot(inr);
  __shared__ int cnt[4];
  if ((threadIdx.x & 63) == 0) cnt[threadIdx.x >> 6] = __popcll(b);
  __syncthreads();
  if (threadIdx.x == 0) *flag = (cnt[0] + cnt[1] + cnt[2] + cnt[3] >= 128) ? 1 : 0;
}

__global__ void bn_params_k(double* stD, float* stF, const void* g, const void* be, int C,
                            double invN, const int* modep) {
  int m = *modep;
  int c = threadIdx.x;
  if (c < C) {
    double mu = stD[c] * invN;
    double var = stD[16 + c] * invN - mu * mu;
    if (var < 0.0) var = 0.0;
    double s = (double)ldv(g, c, m) / sqrt(var + 1e-5);
    double sh = (double)ldv(be, c, m) - mu * s;
    stD[32 + c] = s;  stD[48 + c] = sh;
    stF[c] = (float)s;  stF[16 + c] = (float)sh;
  }
}

// ---- conv1: x (32,1,512,512) -> fp32 (32,16,256,256), k4 s2 p1 ----
__global__ __launch_bounds__(256) void conv1_k(const void* __restrict__ x, const void* __restrict__ w,
                                               const void* __restrict__ bias, float* __restrict__ y,
                                               double* __restrict__ st, const int* modep) {
  const int m = *modep;
  const int co = blockIdx.y;
  __shared__ float wl[16];
  if (threadIdx.x < 16) wl[threadIdx.x] = ldv(w, co * 16 + threadIdx.x, m);
  __syncthreads();
  int idx = blockIdx.x * 256 + threadIdx.x;        // < 32*256*256
  int b = idx >> 16, rem = idx & 65535;
  int oy = rem >> 8, ox = rem & 255;
  size_t xb = (size_t)b * 262144;
  float acc = ldv(bias, co, m);
  int iy0 = 2 * oy - 1, ix0 = 2 * ox - 1;
#pragma unroll
  for (int ky = 0; ky < 4; ky++) {
    int iy = iy0 + ky;
    if ((unsigned)iy < 512u) {
      size_t row = xb + (size_t)iy * 512;
#pragma unroll
      for (int kx = 0; kx < 4; kx++) {
        int ix = ix0 + kx;
        if ((unsigned)ix < 512u) acc = fmaf(wl[ky * 4 + kx], ldv(x, row + ix, m), acc);
      }
    }
  }
  y[((size_t)(b * 16 + co) << 16) + rem] = acc;
  stats_reduce2d((double)acc, (double)acc * (double)acc, st + co, st + 16 + co);
}

// ---- generic stride-2 conv, fp32 in (prev-BN affine+relu on read) ----
template <int CIN, int IH, int CO>
__global__ __launch_bounds__(256) void conv_s2_k(const float* __restrict__ in, const void* __restrict__ w,
                                                 const void* __restrict__ bias, const float* __restrict__ paff,
                                                 float* __restrict__ out, double* __restrict__ st,
                                                 const int* modep) {
  const int m = *modep;
  const int co = blockIdx.y;
  constexpr int OH = IH / 2;
  constexpr int SP = OH * OH;
  __shared__ float wl[CIN * 16];
  __shared__ float sc[CIN], sh[CIN];
  for (int i = threadIdx.x; i < CIN * 16; i += 256) wl[i] = ldv(w, co * CIN * 16 + i, m);
  if (threadIdx.x < CIN) { sc[threadIdx.x] = paff[threadIdx.x]; sh[threadIdx.x] = paff[16 + threadIdx.x]; }
  __syncthreads();
  int idx = blockIdx.x * 256 + threadIdx.x;        // < 32*SP
  int b = idx / SP, rem = idx % SP;
  int oy = rem / OH, ox = rem % OH;
  float acc = ldv(bias, co, m);
  int iy0 = 2 * oy - 1, ix0 = 2 * ox - 1;
  for (int ci = 0; ci < CIN; ci++) {
    const float* ib = in + (size_t)(b * CIN + ci) * IH * IH;
    float s = sc[ci], h = sh[ci];
    const float* wr = wl + ci * 16;
#pragma unroll
    for (int ky = 0; ky < 4; ky++) {
      int iy = iy0 + ky;
      if ((unsigned)iy < (unsigned)IH) {
        const float* row = ib + (size_t)iy * IH;
#pragma unroll
        for (int kx = 0; kx < 4; kx++) {
          int ix = ix0 + kx;
          if ((unsigned)ix < (unsigned)IH) {
            float v = fmaxf(fmaf(row[ix], s, h), 0.f);
            acc = fmaf(v, wr[ky * 4 + kx], acc);
          }
        }
      }
    }
  }
  out[(size_t)(b * CO + co) * SP + rem] = acc;
  stats_reduce2d((double)acc, (double)acc * (double)acc, st + co, st + 16 + co);
}

// ---- VQ fused: BN3 affine+relu -> wpre -> argmin -> quant -> wpost -> d0.
// Near-tie pixels (gap < MARGIN) get flagged for f64 repair. ----
__global__ __launch_bounds__(256) void vq_k(const float* __restrict__ h3, const float* __restrict__ paff,
                                            const void* __restrict__ wpre, const void* __restrict__ bpre,
                                            const void* __restrict__ cbk, const void* __restrict__ wpost,
                                            const void* __restrict__ bpost, float* __restrict__ d0,
                                            double* __restrict__ vacc, int* __restrict__ flagcnt,
                                            Rec* __restrict__ recs, const int* modep) {
  const int m = *modep;
  __shared__ float cb[512];
  for (int i = threadIdx.x; i < 512; i += 256) cb[i] = ldv(cbk, i, m);
  __syncthreads();
  int pix = blockIdx.x * 256 + threadIdx.x;        // < 32*64*64
  int b = pix >> 12, rem = pix & 4095;
  const float* hb = h3 + (size_t)b * 16384 + rem;
  float q0 = ldv(bpre, 0, m), q1 = ldv(bpre, 1, m);
#pragma unroll
  for (int ci = 0; ci < 4; ci++) {
    float v = fmaxf(fmaf(hb[ci * 4096], paff[ci], paff[16 + ci]), 0.f);
    q0 = fmaf(v, ldv(wpre, ci, m), q0);
    q1 = fmaf(v, ldv(wpre, 4 + ci, m), q1);
  }
  int best = 0;
  float bd = 3.4e38f, bd2 = 3.4e38f;
  for (int k = 0; k < 256; k++) {
    float dx = q0 - cb[2 * k], dy = q1 - cb[2 * k + 1];
    float d = dx * dx + dy * dy;
    if (d < bd) { bd2 = bd; bd = d; best = k; }
    else if (d < bd2) bd2 = d;
  }
  float c0 = cb[2 * best], c1 = cb[2 * best + 1];
  float e0 = q0 - c0, e1 = q1 - c1;
  float olde2 = e0 * e0 + e1 * e1;
  float* ob = d0 + (size_t)b * 16384 + rem;
#pragma unroll
  for (int c = 0; c < 4; c++)
    ob[c * 4096] = ldv(bpost, c, m) + ldv(wpost, 2 * c, m) * c0 + ldv(wpost, 2 * c + 1, m) * c1;
  if (bd2 - bd < MARGIN) {
    int slot = atomicAdd(flagcnt, 1);
    if (slot < FLAG_CAP) { recs[slot].pix = pix; recs[slot].e2 = olde2; }
  }
  stats_reduce1d((double)olde2, vacc);
}

// ---- f64 repair of near-tie pixels: recompute q from x over the 22x22 RF ----
__global__ __launch_bounds__(64) void repair_k(const void* __restrict__ x,
    const void* w1, const void* b1, const void* w2, const void* b2,
    const void* w3, const void* b3, const void* wpre, const void* bpre,
    const void* cbk, const void* wpost, const void* bpost,
    const double* __restrict__ STD, float* __restrict__ d0, double* vacc,
    const int* __restrict__ flagcnt, const Rec* __restrict__ recs, const int* modep) {
  const int m = *modep;
  __shared__ double n1[1600];   // [16][10][10]
  __shared__ double n2[256];    // [16][4][4]
  __shared__ double n3[4];
  __shared__ double qq[2];
  __shared__ double cbd[512];
  for (int i = threadIdx.x; i < 512; i += 64) cbd[i] = (double)ldv(cbk, i, m);
  int cnt = *flagcnt; if (cnt > FLAG_CAP) cnt = FLAG_CAP;
  for (int f = blockIdx.x; f < cnt; f += gridDim.x) {
    __syncthreads();
    Rec r = recs[f];
    int b = r.pix >> 12, rem = r.pix & 4095;
    int oy3 = rem >> 6, ox3 = rem & 63;
    // stage1: h1 patch [16][10][10], normalized+relu (OOB = 0)
    for (int idx = threadIdx.x; idx < 1600; idx += 64) {
      int c1 = idx / 100, rr = idx % 100, ry = rr / 10, rx = rr % 10;
      int gy = 4 * oy3 - 3 + ry, gx = 4 * ox3 - 3 + rx;
      double v = 0.0;
      if ((unsigned)gy < 256u && (unsigned)gx < 256u) {
        double a = (double)ldv(b1, c1, m);
        for (int ky = 0; ky < 4; ky++) {
          int iy = 2 * gy - 1 + ky;
          if ((unsigned)iy < 512u) {
            size_t row = (size_t)b * 262144 + (size_t)iy * 512;
            for (int kx = 0; kx < 4; kx++) {
              int ix = 2 * gx - 1 + kx;
              if ((unsigned)ix < 512u)
                a += (double)ldv(w1, c1 * 16 + ky * 4 + kx, m) * (double)ldv(x, row + ix, m);
            }
          }
        }
        v = fmax(STD[32 + c1] * a + STD[48 + c1], 0.0);
      }
      n1[idx] = v;
    }
    __syncthreads();
    // stage2: h2 patch [16][4][4]
    for (int idx = threadIdx.x; idx < 256; idx += 64) {
      int c2 = idx >> 4, rr = idx & 15, ry = rr >> 2, rx = rr & 3;
      int gy = 2 * oy3 - 1 + ry, gx = 2 * ox3 - 1 + rx;
      double v = 0.0;
      if ((unsigned)gy < 128u && (unsigned)gx < 128u) {
        double a = (double)ldv(b2, c2, m);
        for (int ci = 0; ci < 16; ci++) {
          int nb = ci * 100 + 2 * ry * 10 + 2 * rx;
          int wb = (c2 * 16 + ci) * 16;
          for (int ky = 0; ky < 4; ky++)
            for (int kx = 0; kx < 4; kx++)
              a += (double)ldv(w2, wb + ky * 4 + kx, m) * n1[nb + ky * 10 + kx];
        }
        v = fmax(STD[64 + 32 + c2] * a + STD[64 + 48 + c2], 0.0);
      }
      n2[idx] = v;
    }
    __syncthreads();
    // stage3: h3 (4 ch) + q
    if (threadIdx.x < 4) {
      int c3 = threadIdx.x;
      double a = (double)ldv(b3, c3, m);
      for (int ci = 0; ci < 16; ci++) {
        int wb = (c3 * 16 + ci) * 16, nb = ci * 16;
        for (int j = 0; j < 16; j++) a += (double)ldv(w3, wb + j, m) * n2[nb + j];
      }
      n3[c3] = fmax(STD[128 + 32 + c3] * a + STD[128 + 48 + c3], 0.0);
    }
    __syncthreads();
    if (threadIdx.x == 0) {
      double q0 = (double)ldv(bpre, 0, m), q1 = (double)ldv(bpre, 1, m);
      for (int ci = 0; ci < 4; ci++) {
        q0 += n3[ci] * (double)ldv(wpre, ci, m);
        q1 += n3[ci] * (double)ldv(wpre, 4 + ci, m);
      }
      qq[0] = q0; qq[1] = q1;
    }
    __syncthreads();
    double q0 = qq[0], q1 = qq[1];
    double bd = 1e300; int bi = 0;
    for (int k = threadIdx.x * 4; k < threadIdx.x * 4 + 4; k++) {
      double dx = q0 - cbd[2 * k], dy = q1 - cbd[2 * k + 1];
      double d = dx * dx + dy * dy;
      if (d < bd || (d == bd && k < bi)) { bd = d; bi = k; }
    }
#pragma unroll
    for (int off = 32; off; off >>= 1) {
      double od = __shfl_down(bd, off, 64);
      int oi = __shfl_down(bi, off, 64);
      if (od < bd || (od == bd && oi < bi)) { bd = od; bi = oi; }
    }
    if (threadIdx.x == 0) {
      double c0 = cbd[2 * bi], c1 = cbd[2 * bi + 1];
      double e0 = q0 - c0, e1 = q1 - c1;
      atomicAdd(vacc, (e0 * e0 + e1 * e1) - (double)r.e2);
      float* ob = d0 + (size_t)b * 16384 + rem;
      for (int c = 0; c < 4; c++)
        ob[c * 4096] = (float)((double)ldv(bpost, c, m) +
                               (double)ldv(wpost, 2 * c, m) * c0 +
                               (double)ldv(wpost, 2 * c + 1, m) * c1);
    }
  }
}

// ---- ConvTranspose2d k4 s2 p1 gather; weight (CIN, CO, 4, 4) ----
template <int CIN, int IH, int CO, bool AFF>
__global__ __launch_bounds__(256) void deconv_k(const float* __restrict__ in, const void* __restrict__ w,
                                                const void* __restrict__ bias, const float* __restrict__ paff,
                                                float* __restrict__ out, double* __restrict__ st,
                                                const int* modep) {
  const int m = *modep;
  const int co = blockIdx.y;
  constexpr int OH = IH * 2;
  constexpr int SP = OH * OH;
  __shared__ float wl[CIN * 16];
  __shared__ float sc[CIN], sh[CIN];
  for (int i = threadIdx.x; i < CIN * 16; i += 256) wl[i] = ldv(w, ((i >> 4) * CO + co) * 16 + (i & 15), m);
  if (AFF && threadIdx.x < CIN) { sc[threadIdx.x] = paff[threadIdx.x]; sh[threadIdx.x] = paff[16 + threadIdx.x]; }
  __syncthreads();
  int idx = blockIdx.x * 256 + threadIdx.x;        // < 32*SP
  int b = idx / SP, rem = idx % SP;
  int oy = rem / OH, ox = rem % OH;
  float acc = ldv(bias, co, m);
  int ry = (oy + 1) & 1, rx = (ox + 1) & 1;
  for (int ci = 0; ci < CIN; ci++) {
    const float* ib = in + (size_t)(b * CIN + ci) * IH * IH;
    float s = AFF ? sc[ci] : 1.f, h = AFF ? sh[ci] : 0.f;
    const float* wr = wl + ci * 16;
#pragma unroll
    for (int ty = 0; ty < 2; ty++) {
      int ky = ry + 2 * ty;
      int iy = (oy + 1 - ky) >> 1;
      if ((unsigned)iy < (unsigned)IH) {
#pragma unroll
        for (int tx = 0; tx < 2; tx++) {
          int kx = rx + 2 * tx;
          int ix = (ox + 1 - kx) >> 1;
          if ((unsigned)ix < (unsigned)IH) {
            float v = ib[(size_t)iy * IH + ix];
            if (AFF) v = fmaxf(fmaf(v, s, h), 0.f);
            acc = fmaf(v, wr[ky * 4 + kx], acc);
          }
        }
      }
    }
  }
  out[(size_t)(b * CO + co) * SP + rem] = acc;
  stats_reduce2d((double)acc, (double)acc * (double)acc, st + co, st + 16 + co);
}

// ---- final deconv (16 -> 1) + sigmoid + store + recon MSE ----
__global__ __launch_bounds__(256) void deconv3_k(const float* __restrict__ in, const void* __restrict__ w,
                                                 const void* __restrict__ bias, const float* __restrict__ paff,
                                                 const void* __restrict__ x, void* __restrict__ outp,
                                                 double* __restrict__ racc, const int* modep) {
  const int m = *modep;
  __shared__ float wl[256];
  __shared__ float sc[16], sh[16];
  wl[threadIdx.x] = ldv(w, threadIdx.x, m);   // (16,1,4,4) -> wl[ci*16+ky*4+kx]
  if (threadIdx.x < 16) { sc[threadIdx.x] = paff[threadIdx.x]; sh[threadIdx.x] = paff[16 + threadIdx.x]; }
  __syncthreads();
  int idx = blockIdx.x * 256 + threadIdx.x;        // < 32*512*512
  int b = idx >> 18, rem = idx & 262143;
  int oy = rem >> 9, ox = rem & 511;
  float acc = ldv(bias, 0, m);
  int ry = (oy + 1) & 1, rx = (ox + 1) & 1;
  for (int ci = 0; ci < 16; ci++) {
    const float* ib = in + (size_t)(b * 16 + ci) * 65536;
    float s = sc[ci], h = sh[ci];
    const float* wr = wl + ci * 16;
#pragma unroll
    for (int ty = 0; ty < 2; ty++) {
      int ky = ry + 2 * ty;
      int iy = (oy + 1 - ky) >> 1;
      if ((unsigned)iy < 256u) {
#pragma unroll
        for (int tx = 0; tx < 2; tx++) {
          int kx = rx + 2 * tx;
          int ix = (ox + 1 - kx) >> 1;
          if ((unsigned)ix < 256u) {
            float v = fmaxf(fmaf(ib[iy * 256 + ix], s, h), 0.f);
            acc = fmaf(v, wr[ky * 4 + kx], acc);
          }
        }
      }
    }
  }
  float o = 1.f / (1.f + expf(-acc));
  if (m) ((bf16*)outp)[idx] = __float2bfloat16(o);
  else   ((float*)outp)[idx] = o;
  float d = ldv(x, idx, m) - o;
  stats_reduce1d((double)d * (double)d, racc);
}

__global__ void finalize_k(const double* st, void* outp, const int* modep) {
  if (threadIdx.x == 0) {
    double total = st[321] * (1.0 / 8388608.0) + 1.2 * (st[320] * (1.0 / 262144.0));
    if (*modep) ((bf16*)outp)[8388608] = __float2bfloat16((float)total);
    else        ((float*)outp)[8388608] = (float)total;
  }
}

extern "C" void kernel_launch(void* const* d_in, const int* in_sizes, int n_in,
                              void* d_out, int out_size, void* d_ws, size_t ws_size,
                              hipStream_t stream) {
  const void* x    = d_in[0];
  const void* w1   = d_in[1];  const void* b1  = d_in[2];
  const void* g1   = d_in[3];  const void* be1 = d_in[4];
  const void* w2   = d_in[5];  const void* b2  = d_in[6];
  const void* g2   = d_in[7];  const void* be2 = d_in[8];
  const void* w3   = d_in[9];  const void* b3  = d_in[10];
  const void* g3   = d_in[11]; const void* be3 = d_in[12];
  const void* wpre = d_in[13]; const void* bpre= d_in[14];
  const void* cbk  = d_in[15];
  const void* wpost= d_in[16]; const void* bpost= d_in[17];
  const void* wd1  = d_in[18]; const void* bd1 = d_in[19];
  const void* g4   = d_in[20]; const void* be4 = d_in[21];
  const void* wd2  = d_in[22]; const void* bd2 = d_in[23];
  const void* g5   = d_in[24]; const void* be5 = d_in[25];
  const void* wd3  = d_in[26]; const void* bd3 = d_in[27];

  char* ws = (char*)d_ws;
  double* STD = (double*)ws;                       // 512 doubles
  float*  STF = (float*)(ws + 4096);               // 256 floats
  int* FLAGCNT = (int*)(ws + 6144);
  int* MODE    = (int*)(ws + 6148);
  Rec* FLAGS   = (Rec*)(ws + 8192);                // 1MB
  float* A  = (float*)(ws + 4194304);              // h1 / d2  (134MB)
  float* B  = (float*)(ws + 4194304 + 134217728);  // h2 / d1  (33.5MB)
  float* C3 = (float*)(ws + 4194304 + 167772160);  // h3 (2MB)
  float* D0 = (float*)(ws + 4194304 + 169869312);  // d0 (2MB)

  init_k<<<1, 256, 0, stream>>>(STD, FLAGCNT, (const unsigned*)x, MODE);

  conv1_k<<<dim3(8192, 16), 256, 0, stream>>>(x, w1, b1, A, STD + 0, MODE);
  bn_params_k<<<1, 64, 0, stream>>>(STD + 0, STF + 0, g1, be1, 16, 1.0 / 2097152.0, MODE);

  conv_s2_k<16, 256, 16><<<dim3(2048, 16), 256, 0, stream>>>(A, w2, b2, STF + 0, B, STD + 64, MODE);
  bn_params_k<<<1, 64, 0, stream>>>(STD + 64, STF + 32, g2, be2, 16, 1.0 / 524288.0, MODE);

  conv_s2_k<16, 128, 4><<<dim3(512, 4), 256, 0, stream>>>(B, w3, b3, STF + 32, C3, STD + 128, MODE);
  bn_params_k<<<1, 64, 0, stream>>>(STD + 128, STF + 64, g3, be3, 4, 1.0 / 131072.0, MODE);

  vq_k<<<512, 256, 0, stream>>>(C3, STF + 64, wpre, bpre, cbk, wpost, bpost, D0,
                                STD + 320, FLAGCNT, FLAGS, MODE);
  repair_k<<<512, 64, 0, stream>>>(x, w1, b1, w2, b2, w3, b3, wpre, bpre, cbk, wpost, bpost,
                                   STD, D0, STD + 320, FLAGCNT, FLAGS, MODE);

  deconv_k<4, 64, 16, false><<<dim3(2048, 16), 256, 0, stream>>>(D0, wd1, bd1, nullptr, B, STD + 192, MODE);
  bn_params_k<<<1, 64, 0, stream>>>(STD + 192, STF + 96, g4, be4, 16, 1.0 / 524288.0, MODE);

  deconv_k<16, 128, 16, true><<<dim3(8192, 16), 256, 0, stream>>>(B, wd2, bd2, STF + 96, A, STD + 256, MODE);
  bn_params_k<<<1, 64, 0, stream>>>(STD + 256, STF + 128, g5, be5, 16, 1.0 / 2097152.0, MODE);

  deconv3_k<<<32768, 256, 0, stream>>>(A, wd3, bd3, STF + 128, x, d_out, STD + 321, MODE);
  finalize_k<<<1, 64, 0, stream>>>(STD, d_out, MODE);
}

// Round 5
// 1214.976 us; speedup vs baseline: 9.4691x; 9.4691x over previous
//
#include <hip/hip_runtime.h>
#include <hip/hip_bf16.h>
#include <math.h>

using bf16 = __hip_bfloat16;

__device__ __forceinline__ float b2f(bf16 v) { return __bfloat162float(v); }
// mode: 1 = inputs bf16, 0 = inputs f32
__device__ __forceinline__ float ldv(const void* p, size_t i, int m) {
  return m ? b2f(((const bf16*)p)[i]) : ((const float*)p)[i];
}

struct D2 { double s, s2; };

// ---- block reductions (blockDim == 256), non-atomic partial writes ----
__device__ __forceinline__ void block_stats1(float v, D2* slot) {
  float v2 = v * v;
#pragma unroll
  for (int o = 32; o; o >>= 1) { v += __shfl_down(v, o, 64); v2 += __shfl_down(v2, o, 64); }
  __shared__ float a1[4], a2[4];
  int lane = threadIdx.x & 63, w = threadIdx.x >> 6;
  if (lane == 0) { a1[w] = v; a2[w] = v2; }
  __syncthreads();
  if (threadIdx.x == 0) {
    slot->s  = (double)a1[0] + a1[1] + a1[2] + a1[3];
    slot->s2 = (double)a2[0] + a2[1] + a2[2] + a2[3];
  }
}

__device__ __forceinline__ void block_stats1d(double v, double v2, D2* slot) {
#pragma unroll
  for (int o = 32; o; o >>= 1) { v += __shfl_down(v, o, 64); v2 += __shfl_down(v2, o, 64); }
  __shared__ double q1[4], q2[4];
  int lane = threadIdx.x & 63, w = threadIdx.x >> 6;
  if (lane == 0) { q1[w] = v; q2[w] = v2; }
  __syncthreads();
  if (threadIdx.x == 0) { slot->s = q1[0] + q1[1] + q1[2] + q1[3]; slot->s2 = q2[0] + q2[1] + q2[2] + q2[3]; }
}

__device__ __forceinline__ void block_sum1(float v, double* slot) {
#pragma unroll
  for (int o = 32; o; o >>= 1) v += __shfl_down(v, o, 64);
  __shared__ float a1[4];
  int lane = threadIdx.x & 63, w = threadIdx.x >> 6;
  if (lane == 0) a1[w] = v;
  __syncthreads();
  if (threadIdx.x == 0) *slot = (double)a1[0] + a1[1] + a1[2] + a1[3];
}

// 16-channel block stats -> part[co*NB + bx]
__device__ __forceinline__ void block_stats16(const float* vs, const float* vq, D2* base, int NB, int bx) {
  __shared__ float s1[64], s2[64];
  int lane = threadIdx.x & 63, w = threadIdx.x >> 6;
#pragma unroll
  for (int co = 0; co < 16; co++) {
    float v = vs[co], v2 = vq[co];
#pragma unroll
    for (int o = 32; o; o >>= 1) { v += __shfl_down(v, o, 64); v2 += __shfl_down(v2, o, 64); }
    if (lane == 0) { s1[co * 4 + w] = v; s2[co * 4 + w] = v2; }
  }
  __syncthreads();
  if (threadIdx.x < 16) {
    int co = threadIdx.x;
    base[co * NB + bx].s  = (double)s1[co * 4] + s1[co * 4 + 1] + s1[co * 4 + 2] + s1[co * 4 + 3];
    base[co * NB + bx].s2 = (double)s2[co * 4] + s2[co * 4 + 1] + s2[co * 4 + 2] + s2[co * 4 + 3];
  }
}

// ---- dtype detect ----
__global__ void init_k(const unsigned* __restrict__ xw, int* flag) {
  unsigned lo = xw[threadIdx.x] & 0xFFFFu;
  int inr = (lo >= 0x3000u && lo < 0x4000u) ? 1 : 0;
  unsigned long long b = __ballot(inr);
  __shared__ int cnt[4];
  if ((threadIdx.x & 63) == 0) cnt[threadIdx.x >> 6] = __popcll(b);
  __syncthreads();
  if (threadIdx.x == 0) *flag = (cnt[0] + cnt[1] + cnt[2] + cnt[3] >= 128) ? 1 : 0;
}

// PF float layout: W1 0(256) B1 256(16) W2 272(4096,[co*256+ci*16+tap]) B2 4368(16)
//   WD1 4384(1024,[co*64+ci*16+tap]) BD1 5408(16) WD2 5424(4096,[co*256+ci*16+tap])
//   BD2 9520(16) WD3 9536(256,[ci*16+tap]) BD3 9792(1) G/BE 9856+l*32 (gamma 16, beta 16)
// PD double layout: W3 0(1024,[co*256+ci*16+tap]) B3 1024(4) WPRE 1028(8) BPRE 1036(2)
//   CB 1040(512) WPOST 1552(8) BPOST 1560(4)
__global__ void prep_k(const void* w1, const void* b1, const void* w2, const void* b2,
                       const void* w3, const void* b3, const void* wpre, const void* bpre,
                       const void* cbk, const void* wpost, const void* bpost,
                       const void* wd1, const void* bd1, const void* wd2, const void* bd2,
                       const void* wd3, const void* bd3,
                       const void* g1, const void* be1, const void* g2, const void* be2,
                       const void* g3, const void* be3, const void* g4, const void* be4,
                       const void* g5, const void* be5,
                       float* __restrict__ PF, double* __restrict__ PD, const int* modep) {
  int m = *modep, t = threadIdx.x;
  for (int i = t; i < 256; i += 256) PF[i] = ldv(w1, i, m);
  if (t < 16) PF[256 + t] = ldv(b1, t, m);
  for (int i = t; i < 4096; i += 256) PF[272 + i] = ldv(w2, i, m);
  if (t < 16) PF[4368 + t] = ldv(b2, t, m);
  for (int i = t; i < 1024; i += 256) {   // wd1 (4,16,4,4) -> [co*64+ci*16+tap]
    int co = i >> 6, ci = (i >> 4) & 3, tap = i & 15;
    PF[4384 + i] = ldv(wd1, ci * 256 + co * 16 + tap, m);
  }
  if (t < 16) PF[5408 + t] = ldv(bd1, t, m);
  for (int i = t; i < 4096; i += 256) {   // wd2 (16,16,4,4) -> [co*256+ci*16+tap]
    int co = i >> 8, ci = (i >> 4) & 15, tap = i & 15;
    PF[5424 + i] = ldv(wd2, ci * 256 + co * 16 + tap, m);
  }
  if (t < 16) PF[9520 + t] = ldv(bd2, t, m);
  for (int i = t; i < 256; i += 256) PF[9536 + i] = ldv(wd3, i, m);
  if (t == 0) PF[9792] = ldv(bd3, 0, m);
  if (t < 16) {
    PF[9856 + t] = ldv(g1, t, m);  PF[9872 + t] = ldv(be1, t, m);
    PF[9888 + t] = ldv(g2, t, m);  PF[9904 + t] = ldv(be2, t, m);
    PF[9952 + t] = ldv(g4, t, m);  PF[9968 + t] = ldv(be4, t, m);
    PF[9984 + t] = ldv(g5, t, m);  PF[10000 + t] = ldv(be5, t, m);
  }
  if (t < 4) { PF[9920 + t] = ldv(g3, t, m); PF[9936 + t] = ldv(be3, t, m); }
  for (int i = t; i < 1024; i += 256) PD[i] = ldv(w3, i, m);
  if (t < 4) PD[1024 + t] = ldv(b3, t, m);
  if (t < 8) PD[1028 + t] = ldv(wpre, t, m);
  if (t < 2) PD[1036 + t] = ldv(bpre, t, m);
  for (int i = t; i < 512; i += 256) PD[1040 + i] = ldv(cbk, i, m);
  if (t < 8) PD[1552 + t] = ldv(wpost, t, m);
  if (t < 4) PD[1560 + t] = ldv(bpost, t, m);
}

// ---- BN reduce: partials -> scale/shift (f64 + f32) ----
__global__ __launch_bounds__(256) void bn_reduce_k(const D2* __restrict__ part, int NB,
                                                   double* __restrict__ stD, float* __restrict__ stF,
                                                   const float* __restrict__ gb, double invN) {
  int c = blockIdx.x;
  double s = 0, s2 = 0;
  for (int i = threadIdx.x; i < NB; i += 256) { D2 p = part[c * NB + i]; s += p.s; s2 += p.s2; }
#pragma unroll
  for (int o = 32; o; o >>= 1) { s += __shfl_down(s, o, 64); s2 += __shfl_down(s2, o, 64); }
  __shared__ double l1[4], l2[4];
  int lane = threadIdx.x & 63, w = threadIdx.x >> 6;
  if (lane == 0) { l1[w] = s; l2[w] = s2; }
  __syncthreads();
  if (threadIdx.x == 0) {
    double S = l1[0] + l1[1] + l1[2] + l1[3], Q = l2[0] + l2[1] + l2[2] + l2[3];
    double mu = S * invN, var = Q * invN - mu * mu;
    if (var < 0) var = 0;
    double sc = (double)gb[c] / sqrt(var + 1e-5);
    double sh = (double)gb[16 + c] - mu * sc;
    stD[c] = sc; stD[16 + c] = sh;
    stF[c] = (float)sc; stF[16 + c] = (float)sh;
  }
}

// ---- conv1: x (32,1,512,512) -> f32 (32,16,256,256), k4 s2 p1 ----
__global__ __launch_bounds__(256) void conv1_k(const void* __restrict__ x, const float* __restrict__ PF,
                                               float* __restrict__ y, D2* __restrict__ part,
                                               const int* modep) {
  const int m = *modep;
  const int co = blockIdx.y;
  int idx = blockIdx.x * 256 + threadIdx.x;
  int b = idx >> 16, rem = idx & 65535, oy = rem >> 8, ox = rem & 255;
  size_t xb = (size_t)b * 262144;
  float acc = PF[256 + co];
  int iy0 = 2 * oy - 1, ix0 = 2 * ox - 1;
#pragma unroll
  for (int ky = 0; ky < 4; ky++) {
    int iy = iy0 + ky;
    if ((unsigned)iy < 512u) {
      size_t row = xb + (size_t)iy * 512;
#pragma unroll
      for (int kx = 0; kx < 4; kx++) {
        int ix = ix0 + kx;
        if ((unsigned)ix < 512u) acc = fmaf(PF[co * 16 + ky * 4 + kx], ldv(x, row + ix, m), acc);
      }
    }
  }
  y[((size_t)(b * 16 + co) << 16) + rem] = acc;
  block_stats1(acc, part + (co * 8192 + blockIdx.x));
}

// ---- conv2 tiled: all 16 co per block, 16x16 tile, LDS staged per-ci ----
__global__ __launch_bounds__(256) void conv2_t(const float* __restrict__ h1, const float* __restrict__ PF,
                                               const float* __restrict__ aff, float* __restrict__ h2,
                                               D2* __restrict__ part) {
  __shared__ float su[34 * 34];
  int t = threadIdx.x, ty = t >> 4, tx = t & 15;
  int bx = blockIdx.x, bb = bx >> 6, r = bx & 63, tY = r >> 3, tX = r & 7;
  int oy = tY * 16 + ty, ox = tX * 16 + tx;
  int iy0 = 32 * tY - 1, ix0 = 32 * tX - 1;
  const float* W2 = PF + 272;
  float acc[16];
#pragma unroll
  for (int co = 0; co < 16; co++) acc[co] = PF[4368 + co];
  for (int ci = 0; ci < 16; ci++) {
    __syncthreads();
    float sc = aff[ci], sh = aff[16 + ci];
    const float* ib = h1 + ((size_t)(bb * 16 + ci) << 16);
    for (int i = t; i < 1156; i += 256) {
      int riy = i / 34, rix = i - riy * 34;
      int gy = iy0 + riy, gx = ix0 + rix;
      float v = 0.f;
      if ((unsigned)gy < 256u && (unsigned)gx < 256u) v = fmaxf(fmaf(ib[gy * 256 + gx], sc, sh), 0.f);
      su[i] = v;
    }
    __syncthreads();
    const float* wci = W2 + ci * 16;
#pragma unroll
    for (int ky = 0; ky < 4; ky++) {
#pragma unroll
      for (int kx = 0; kx < 4; kx++) {
        float v = su[(2 * ty + ky) * 34 + 2 * tx + kx];
        const float* wt = wci + ky * 4 + kx;
#pragma unroll
        for (int co = 0; co < 16; co++) acc[co] = fmaf(v, wt[co * 256], acc[co]);
      }
    }
  }
  float vq_[16];
#pragma unroll
  for (int co = 0; co < 16; co++) {
    h2[((size_t)(bb * 16 + co) * 128 + oy) * 128 + ox] = acc[co];
    vq_[co] = acc[co] * acc[co];
  }
  block_stats16(acc, vq_, part, 2048, bx);
}

// ---- conv3: f32 h2 (affine2+relu) -> f64 raw conv out (32,4,64,64) ----
__global__ __launch_bounds__(256) void conv3_k(const float* __restrict__ h2, const double* __restrict__ PD,
                                               const float* __restrict__ aff, double* __restrict__ c3,
                                               D2* __restrict__ part) {
  const int co = blockIdx.y;
  int idx = blockIdx.x * 256 + threadIdx.x;   // 131072
  int b = idx >> 12, rem = idx & 4095, oy = rem >> 6, ox = rem & 63;
  double acc = PD[1024 + co];
  int iy0 = 2 * oy - 1, ix0 = 2 * ox - 1;
  for (int ci = 0; ci < 16; ci++) {
    const float* ib = h2 + (size_t)(b * 16 + ci) * 16384;
    float sc = aff[ci], sh = aff[16 + ci];
    const double* wr = PD + co * 256 + ci * 16;
#pragma unroll
    for (int ky = 0; ky < 4; ky++) {
      int iy = iy0 + ky;
      if ((unsigned)iy < 128u) {
        const float* row = ib + iy * 128;
#pragma unroll
        for (int kx = 0; kx < 4; kx++) {
          int ix = ix0 + kx;
          if ((unsigned)ix < 128u) {
            float v = fmaxf(fmaf(row[ix], sc, sh), 0.f);
            acc = fma((double)v, wr[ky * 4 + kx], acc);
          }
        }
      }
    }
  }
  c3[(size_t)(b * 4 + co) * 4096 + rem] = acc;
  block_stats1d(acc, acc * acc, part + (co * 512 + blockIdx.x));
}

// ---- VQ: f64 BN3 affine+relu -> wpre -> argmin -> wpost -> d0 (f32) ----
__global__ __launch_bounds__(256) void vq_k(const double* __restrict__ c3, const double* __restrict__ PD,
                                            const double* __restrict__ stD2, float* __restrict__ d0,
                                            double* __restrict__ vp) {
  __shared__ double cb[512];
  for (int i = threadIdx.x; i < 512; i += 256) cb[i] = PD[1040 + i];
  __syncthreads();
  int pix = blockIdx.x * 256 + threadIdx.x;
  int b = pix >> 12, rem = pix & 4095;
  const double* hb = c3 + (size_t)b * 16384 + rem;
  double q0 = PD[1036], q1 = PD[1037];
#pragma unroll
  for (int ci = 0; ci < 4; ci++) {
    double v = fma(hb[ci * 4096], stD2[ci], stD2[16 + ci]);
    if (v < 0) v = 0;
    q0 = fma(v, PD[1028 + ci], q0);
    q1 = fma(v, PD[1032 + ci], q1);
  }
  int best = 0;
  double bd = 1e300;
  for (int k = 0; k < 256; k++) {
    double dx = q0 - cb[2 * k], dy = q1 - cb[2 * k + 1];
    double d = dx * dx + dy * dy;
    if (d < bd) { bd = d; best = k; }   // strict < == first-index argmin
  }
  double c0 = cb[2 * best], c1 = cb[2 * best + 1];
  double e0 = q0 - c0, e1 = q1 - c1;
  float* ob = d0 + (size_t)b * 16384 + rem;
#pragma unroll
  for (int c = 0; c < 4; c++)
    ob[c * 4096] = (float)(PD[1560 + c] + PD[1552 + 2 * c] * c0 + PD[1552 + 2 * c + 1] * c1);
  double v = e0 * e0 + e1 * e1;
#pragma unroll
  for (int o = 32; o; o >>= 1) v += __shfl_down(v, o, 64);
  __shared__ double l1[4];
  int lane = threadIdx.x & 63, w = threadIdx.x >> 6;
  if (lane == 0) l1[w] = v;
  __syncthreads();
  if (threadIdx.x == 0) vp[blockIdx.x] = l1[0] + l1[1] + l1[2] + l1[3];
}

// ---- deconv1: d0 (32,4,64,64) -> d1 raw (32,16,128,128), per-px ----
__global__ __launch_bounds__(256) void deconv1_k(const float* __restrict__ d0, const float* __restrict__ PF,
                                                 float* __restrict__ d1, D2* __restrict__ part) {
  const int co = blockIdx.y;
  __shared__ float wl[64];
  if (threadIdx.x < 64) wl[threadIdx.x] = PF[4384 + co * 64 + threadIdx.x];
  __syncthreads();
  int idx = blockIdx.x * 256 + threadIdx.x;   // 524288
  int b = idx >> 14, rem = idx & 16383, oy = rem >> 7, ox = rem & 127;
  float acc = PF[5408 + co];
  int ry = (oy + 1) & 1, rx = (ox + 1) & 1;
#pragma unroll
  for (int ci = 0; ci < 4; ci++) {
    const float* ib = d0 + (size_t)(b * 4 + ci) * 4096;
    const float* wr = wl + ci * 16;
#pragma unroll
    for (int t2y = 0; t2y < 2; t2y++) {
      int ky = ry + 2 * t2y, iy = (oy + 1 - ky) >> 1;
      if ((unsigned)iy < 64u) {
#pragma unroll
        for (int t2x = 0; t2x < 2; t2x++) {
          int kx = rx + 2 * t2x, ix = (ox + 1 - kx) >> 1;
          if ((unsigned)ix < 64u) acc = fmaf(ib[iy * 64 + ix], wr[ky * 4 + kx], acc);
        }
      }
    }
  }
  d1[(size_t)(b * 16 + co) * 16384 + rem] = acc;
  block_stats1(acc, part + (co * 2048 + blockIdx.x));
}

// ---- deconv2 tiled: 2x2 quad per thread, 32x32 tile, all 16 co ----
__global__ __launch_bounds__(256) void deconv2_t(const float* __restrict__ d1, const float* __restrict__ PF,
                                                 const float* __restrict__ aff, float* __restrict__ d2,
                                                 D2* __restrict__ part) {
  __shared__ float su[16 * 324];
  int t = threadIdx.x, qy = t >> 4, qx = t & 15;
  int bx = blockIdx.x, bb = bx >> 6, r = bx & 63, tY = r >> 3, tX = r & 7;
  int oy0 = 32 * tY, ox0 = 32 * tX;
  int iy0 = 16 * tY - 1, ix0 = 16 * tX - 1;
  for (int i = t; i < 5184; i += 256) {
    int ci = i / 324, rr = i - ci * 324;
    int riy = rr / 18, rix = rr - riy * 18;
    int gy = iy0 + riy, gx = ix0 + rix;
    float v = 0.f;
    if ((unsigned)gy < 128u && (unsigned)gx < 128u)
      v = fmaxf(fmaf(d1[(size_t)(bb * 16 + ci) * 16384 + gy * 128 + gx], aff[ci], aff[16 + ci]), 0.f);
    su[i] = v;
  }
  __syncthreads();
  const float* WD2 = PF + 5424;
  float acc[4][16];
#pragma unroll
  for (int p = 0; p < 4; p++)
#pragma unroll
    for (int co = 0; co < 16; co++) acc[p][co] = PF[9520 + co];
  for (int ci = 0; ci < 16; ci++) {
    float sv[3][3];
#pragma unroll
    for (int dy = 0; dy < 3; dy++)
#pragma unroll
      for (int dx = 0; dx < 3; dx++) sv[dy][dx] = su[ci * 324 + (qy + dy) * 18 + (qx + dx)];
    const float* wci = WD2 + ci * 16;
#pragma unroll
    for (int a = 0; a < 2; a++)
#pragma unroll
      for (int bc = 0; bc < 2; bc++) {
        int p = a * 2 + bc;
#pragma unroll
        for (int t2y = 0; t2y < 2; t2y++) {
          int ky = 1 - a + 2 * t2y, dy = 1 + a - t2y;
#pragma unroll
          for (int t2x = 0; t2x < 2; t2x++) {
            int kx = 1 - bc + 2 * t2x, dx = 1 + bc - t2x;
            float v = sv[dy][dx];
            const float* wt = wci + ky * 4 + kx;
#pragma unroll
            for (int co = 0; co < 16; co++) acc[p][co] = fmaf(v, wt[co * 256], acc[p][co]);
          }
        }
      }
  }
#pragma unroll
  for (int a = 0; a < 2; a++)
#pragma unroll
    for (int bc = 0; bc < 2; bc++) {
      int oy = oy0 + 2 * qy + a, ox = ox0 + 2 * qx + bc, p = a * 2 + bc;
#pragma unroll
      for (int co = 0; co < 16; co++)
        d2[((size_t)(bb * 16 + co) * 256 + oy) * 256 + ox] = acc[p][co];
    }
  float vs[16], vqq[16];
#pragma unroll
  for (int co = 0; co < 16; co++) {
    vs[co]  = acc[0][co] + acc[1][co] + acc[2][co] + acc[3][co];
    vqq[co] = acc[0][co] * acc[0][co] + acc[1][co] * acc[1][co] +
              acc[2][co] * acc[2][co] + acc[3][co] * acc[3][co];
  }
  block_stats16(vs, vqq, part, 2048, bx);
}

// ---- deconv3 (16->1) + sigmoid + store + recon MSE partial ----
__global__ __launch_bounds__(256) void deconv3_k(const float* __restrict__ d2, const float* __restrict__ PF,
                                                 const float* __restrict__ aff, const void* __restrict__ x,
                                                 void* __restrict__ outp, double* __restrict__ rp,
                                                 const int* modep) {
  const int m = *modep;
  __shared__ float wl[256], sc[16], sh[16];
  wl[threadIdx.x] = PF[9536 + threadIdx.x];
  if (threadIdx.x < 16) { sc[threadIdx.x] = aff[threadIdx.x]; sh[threadIdx.x] = aff[16 + threadIdx.x]; }
  __syncthreads();
  int idx = blockIdx.x * 256 + threadIdx.x;
  int b = idx >> 18, rem = idx & 262143, oy = rem >> 9, ox = rem & 511;
  float acc = PF[9792];
  int ry = (oy + 1) & 1, rx = (ox + 1) & 1;
  for (int ci = 0; ci < 16; ci++) {
    const float* ib = d2 + (size_t)(b * 16 + ci) * 65536;
    float s = sc[ci], h = sh[ci];
    const float* wr = wl + ci * 16;
#pragma unroll
    for (int t2y = 0; t2y < 2; t2y++) {
      int ky = ry + 2 * t2y, iy = (oy + 1 - ky) >> 1;
      if ((unsigned)iy < 256u) {
#pragma unroll
        for (int t2x = 0; t2x < 2; t2x++) {
          int kx = rx + 2 * t2x, ix = (ox + 1 - kx) >> 1;
          if ((unsigned)ix < 256u) {
            float v = fmaxf(fmaf(ib[iy * 256 + ix], s, h), 0.f);
            acc = fmaf(v, wr[ky * 4 + kx], acc);
          }
        }
      }
    }
  }
  float o = 1.f / (1.f + expf(-acc));
  if (m) ((bf16*)outp)[idx] = __float2bfloat16(o);
  else   ((float*)outp)[idx] = o;
  float d = ldv(x, idx, m) - o;
  block_sum1(d * d, rp + blockIdx.x);
}

__global__ __launch_bounds__(256) void finalize_k(const double* __restrict__ vp, const double* __restrict__ rp,
                                                  void* outp, const int* modep) {
  double s = 0, rr = 0;
  for (int i = threadIdx.x; i < 512; i += 256) s += vp[i];
  for (int i = threadIdx.x; i < 32768; i += 256) rr += rp[i];
#pragma unroll
  for (int o = 32; o; o >>= 1) { s += __shfl_down(s, o, 64); rr += __shfl_down(rr, o, 64); }
  __shared__ double l1[4], l2[4];
  int lane = threadIdx.x & 63, w = threadIdx.x >> 6;
  if (lane == 0) { l1[w] = s; l2[w] = rr; }
  __syncthreads();
  if (threadIdx.x == 0) {
    double S = l1[0] + l1[1] + l1[2] + l1[3], R = l2[0] + l2[1] + l2[2] + l2[3];
    double total = R * (1.0 / 8388608.0) + 1.2 * (S * (1.0 / 262144.0));
    if (*modep) ((bf16*)outp)[8388608] = __float2bfloat16((float)total);
    else        ((float*)outp)[8388608] = (float)total;
  }
}

extern "C" void kernel_launch(void* const* d_in, const int* in_sizes, int n_in,
                              void* d_out, int out_size, void* d_ws, size_t ws_size,
                              hipStream_t stream) {
  const void* x    = d_in[0];
  const void* w1   = d_in[1];  const void* b1  = d_in[2];
  const void* g1   = d_in[3];  const void* be1 = d_in[4];
  const void* w2   = d_in[5];  const void* b2  = d_in[6];
  const void* g2   = d_in[7];  const void* be2 = d_in[8];
  const void* w3   = d_in[9];  const void* b3  = d_in[10];
  const void* g3   = d_in[11]; const void* be3 = d_in[12];
  const void* wpre = d_in[13]; const void* bpre= d_in[14];
  const void* cbk  = d_in[15];
  const void* wpost= d_in[16]; const void* bpost= d_in[17];
  const void* wd1  = d_in[18]; const void* bd1 = d_in[19];
  const void* g4   = d_in[20]; const void* be4 = d_in[21];
  const void* wd2  = d_in[22]; const void* bd2 = d_in[23];
  const void* g5   = d_in[24]; const void* be5 = d_in[25];
  const void* wd3  = d_in[26]; const void* bd3 = d_in[27];

  char* ws = (char*)d_ws;
  int*    MODE = (int*)ws;
  float*  STF  = (float*)(ws + 1024);      // 5 layers x 32 f
  double* STD  = (double*)(ws + 4096);     // 5 layers x 32 d
  float*  PF   = (float*)(ws + 8192);
  double* PD   = (double*)(ws + 73728);
  D2*     P1   = (D2*)(ws + 131072);       // 16*8192
  D2*     P2   = (D2*)(ws + 2228224);      // 16*2048
  D2*     P3   = (D2*)(ws + 2752512);      // 4*512
  D2*     P4   = (D2*)(ws + 2785280);      // 16*2048
  D2*     P5   = (D2*)(ws + 3309568);      // 16*2048
  double* VP   = (double*)(ws + 3833856);  // 512
  double* RP   = (double*)(ws + 3837952);  // 32768
  char* HB = ws + 6291456;
  float*  H1  = (float*)HB;                       // 134 MB
  float*  H2  = (float*)(HB + 134217728);         // 33.5 MB
  double* C3  = (double*)HB;                      // 4 MB, reuses dead H1
  float*  D0  = (float*)(HB + 165675008);         // 2 MB, inside dead H2
  float*  D1  = (float*)HB;                       // reuses dead C3
  float*  D2T = (float*)(HB + 33554432);          // 134 MB, overwrites dead H2/D0

  init_k<<<1, 256, 0, stream>>>((const unsigned*)x, MODE);
  prep_k<<<1, 256, 0, stream>>>(w1, b1, w2, b2, w3, b3, wpre, bpre, cbk, wpost, bpost,
                                wd1, bd1, wd2, bd2, wd3, bd3,
                                g1, be1, g2, be2, g3, be3, g4, be4, g5, be5, PF, PD, MODE);

  conv1_k<<<dim3(8192, 16), 256, 0, stream>>>(x, PF, H1, P1, MODE);
  bn_reduce_k<<<16, 256, 0, stream>>>(P1, 8192, STD + 0, STF + 0, PF + 9856, 1.0 / 2097152.0);

  conv2_t<<<2048, 256, 0, stream>>>(H1, PF, STF + 0, H2, P2);
  bn_reduce_k<<<16, 256, 0, stream>>>(P2, 2048, STD + 32, STF + 32, PF + 9888, 1.0 / 524288.0);

  conv3_k<<<dim3(512, 4), 256, 0, stream>>>(H2, PD, STF + 32, C3, P3);
  bn_reduce_k<<<4, 256, 0, stream>>>(P3, 512, STD + 64, STF + 64, PF + 9920, 1.0 / 131072.0);

  vq_k<<<512, 256, 0, stream>>>(C3, PD, STD + 64, D0, VP);

  deconv1_k<<<dim3(2048, 16), 256, 0, stream>>>(D0, PF, D1, P4);
  bn_reduce_k<<<16, 256, 0, stream>>>(P4, 2048, STD + 96, STF + 96, PF + 9952, 1.0 / 524288.0);

  deconv2_t<<<2048, 256, 0, stream>>>(D1, PF, STF + 96, D2T, P5);
  bn_reduce_k<<<16, 256, 0, stream>>>(P5, 2048, STD + 128, STF + 128, PF + 9984, 1.0 / 2097152.0);

  deconv3_k<<<32768, 256, 0, stream>>>(D2T, PF, STF + 128, x, d_out, RP, MODE);
  finalize_k<<<1, 256, 0, stream>>>(VP, RP, d_out, MODE);
}

// Round 7
// 960.462 us; speedup vs baseline: 11.9783x; 1.2650x over previous
//
#include <hip/hip_runtime.h>
#include <hip/hip_bf16.h>
#include <math.h>

using bf16 = __hip_bfloat16;

__device__ __forceinline__ float b2f(bf16 v) { return __bfloat162float(v); }
// mode: 1 = inputs bf16, 0 = inputs f32
__device__ __forceinline__ float ldv(const void* p, size_t i, int m) {
  return m ? b2f(((const bf16*)p)[i]) : ((const float*)p)[i];
}

struct D2 { double s, s2; };

// ---- block reductions (blockDim == 256), non-atomic partial writes ----
__device__ __forceinline__ void block_stats1(float v, D2* slot) {
  float v2 = v * v;
#pragma unroll
  for (int o = 32; o; o >>= 1) { v += __shfl_down(v, o, 64); v2 += __shfl_down(v2, o, 64); }
  __shared__ float a1[4], a2[4];
  int lane = threadIdx.x & 63, w = threadIdx.x >> 6;
  if (lane == 0) { a1[w] = v; a2[w] = v2; }
  __syncthreads();
  if (threadIdx.x == 0) {
    slot->s  = (double)a1[0] + a1[1] + a1[2] + a1[3];
    slot->s2 = (double)a2[0] + a2[1] + a2[2] + a2[3];
  }
}

__device__ __forceinline__ void block_stats1d(double v, double v2, D2* slot) {
#pragma unroll
  for (int o = 32; o; o >>= 1) { v += __shfl_down(v, o, 64); v2 += __shfl_down(v2, o, 64); }
  __shared__ double q1[4], q2[4];
  int lane = threadIdx.x & 63, w = threadIdx.x >> 6;
  if (lane == 0) { q1[w] = v; q2[w] = v2; }
  __syncthreads();
  if (threadIdx.x == 0) { slot->s = q1[0] + q1[1] + q1[2] + q1[3]; slot->s2 = q2[0] + q2[1] + q2[2] + q2[3]; }
}

__device__ __forceinline__ void block_sum1(float v, double* slot) {
#pragma unroll
  for (int o = 32; o; o >>= 1) v += __shfl_down(v, o, 64);
  __shared__ float a1[4];
  int lane = threadIdx.x & 63, w = threadIdx.x >> 6;
  if (lane == 0) a1[w] = v;
  __syncthreads();
  if (threadIdx.x == 0) *slot = (double)a1[0] + a1[1] + a1[2] + a1[3];
}

// 16-channel block stats -> part[co*NB + bx]
__device__ __forceinline__ void block_stats16(const float* vs, const float* vq, D2* base, int NB, int bx) {
  __shared__ float s1[64], s2[64];
  int lane = threadIdx.x & 63, w = threadIdx.x >> 6;
#pragma unroll
  for (int co = 0; co < 16; co++) {
    float v = vs[co], v2 = vq[co];
#pragma unroll
    for (int o = 32; o; o >>= 1) { v += __shfl_down(v, o, 64); v2 += __shfl_down(v2, o, 64); }
    if (lane == 0) { s1[co * 4 + w] = v; s2[co * 4 + w] = v2; }
  }
  __syncthreads();
  if (threadIdx.x < 16) {
    int co = threadIdx.x;
    base[co * NB + bx].s  = (double)s1[co * 4] + s1[co * 4 + 1] + s1[co * 4 + 2] + s1[co * 4 + 3];
    base[co * NB + bx].s2 = (double)s2[co * 4] + s2[co * 4 + 1] + s2[co * 4 + 2] + s2[co * 4 + 3];
  }
}

// ---- dtype detect ----
__global__ void init_k(const unsigned* __restrict__ xw, int* flag) {
  unsigned lo = xw[threadIdx.x] & 0xFFFFu;
  int inr = (lo >= 0x3000u && lo < 0x4000u) ? 1 : 0;
  unsigned long long b = __ballot(inr);
  __shared__ int cnt[4];
  if ((threadIdx.x & 63) == 0) cnt[threadIdx.x >> 6] = __popcll(b);
  __syncthreads();
  if (threadIdx.x == 0) *flag = (cnt[0] + cnt[1] + cnt[2] + cnt[3] >= 128) ? 1 : 0;
}

// PF float layout: W1 0(256) B1 256(16) W2 272(4096,[co*256+ci*16+tap]) B2 4368(16)
//   WD1 4384(1024,[co*64+ci*16+tap]) BD1 5408(16) WD2 5424(4096,[co*256+ci*16+tap])
//   BD2 9520(16) WD3 9536(256,[ci*16+tap]) BD3 9792(1) G/BE 9856+l*32 (gamma 16, beta 16)
// PD double layout: W3 0(1024,[co*256+ci*16+tap]) B3 1024(4) WPRE 1028(8) BPRE 1036(2)
//   CB 1040(512) WPOST 1552(8) BPOST 1560(4)
__global__ void prep_k(const void* w1, const void* b1, const void* w2, const void* b2,
                       const void* w3, const void* b3, const void* wpre, const void* bpre,
                       const void* cbk, const void* wpost, const void* bpost,
                       const void* wd1, const void* bd1, const void* wd2, const void* bd2,
                       const void* wd3, const void* bd3,
                       const void* g1, const void* be1, const void* g2, const void* be2,
                       const void* g3, const void* be3, const void* g4, const void* be4,
                       const void* g5, const void* be5,
                       float* __restrict__ PF, double* __restrict__ PD, const int* modep) {
  int m = *modep, t = threadIdx.x;
  for (int i = t; i < 256; i += 256) PF[i] = ldv(w1, i, m);
  if (t < 16) PF[256 + t] = ldv(b1, t, m);
  for (int i = t; i < 4096; i += 256) PF[272 + i] = ldv(w2, i, m);
  if (t < 16) PF[4368 + t] = ldv(b2, t, m);
  for (int i = t; i < 1024; i += 256) {   // wd1 (4,16,4,4) -> [co*64+ci*16+tap]
    int co = i >> 6, ci = (i >> 4) & 3, tap = i & 15;
    PF[4384 + i] = ldv(wd1, ci * 256 + co * 16 + tap, m);
  }
  if (t < 16) PF[5408 + t] = ldv(bd1, t, m);
  for (int i = t; i < 4096; i += 256) {   // wd2 (16,16,4,4) -> [co*256+ci*16+tap]
    int co = i >> 8, ci = (i >> 4) & 15, tap = i & 15;
    PF[5424 + i] = ldv(wd2, ci * 256 + co * 16 + tap, m);
  }
  if (t < 16) PF[9520 + t] = ldv(bd2, t, m);
  for (int i = t; i < 256; i += 256) PF[9536 + i] = ldv(wd3, i, m);
  if (t == 0) PF[9792] = ldv(bd3, 0, m);
  if (t < 16) {
    PF[9856 + t] = ldv(g1, t, m);  PF[9872 + t] = ldv(be1, t, m);
    PF[9888 + t] = ldv(g2, t, m);  PF[9904 + t] = ldv(be2, t, m);
    PF[9952 + t] = ldv(g4, t, m);  PF[9968 + t] = ldv(be4, t, m);
    PF[9984 + t] = ldv(g5, t, m);  PF[10000 + t] = ldv(be5, t, m);
  }
  if (t < 4) { PF[9920 + t] = ldv(g3, t, m); PF[9936 + t] = ldv(be3, t, m); }
  for (int i = t; i < 1024; i += 256) PD[i] = ldv(w3, i, m);
  if (t < 4) PD[1024 + t] = ldv(b3, t, m);
  if (t < 8) PD[1028 + t] = ldv(wpre, t, m);
  if (t < 2) PD[1036 + t] = ldv(bpre, t, m);
  for (int i = t; i < 512; i += 256) PD[1040 + i] = ldv(cbk, i, m);
  if (t < 8) PD[1552 + t] = ldv(wpost, t, m);
  if (t < 4) PD[1560 + t] = ldv(bpost, t, m);
}

// ---- BN reduce: partials -> scale/shift (f64 + f32) ----
__global__ __launch_bounds__(256) void bn_reduce_k(const D2* __restrict__ part, int NB,
                                                   double* __restrict__ stD, float* __restrict__ stF,
                                                   const float* __restrict__ gb, double invN) {
  int c = blockIdx.x;
  double s = 0, s2 = 0;
  for (int i = threadIdx.x; i < NB; i += 256) { D2 p = part[c * NB + i]; s += p.s; s2 += p.s2; }
#pragma unroll
  for (int o = 32; o; o >>= 1) { s += __shfl_down(s, o, 64); s2 += __shfl_down(s2, o, 64); }
  __shared__ double l1[4], l2[4];
  int lane = threadIdx.x & 63, w = threadIdx.x >> 6;
  if (lane == 0) { l1[w] = s; l2[w] = s2; }
  __syncthreads();
  if (threadIdx.x == 0) {
    double S = l1[0] + l1[1] + l1[2] + l1[3], Q = l2[0] + l2[1] + l2[2] + l2[3];
    double mu = S * invN, var = Q * invN - mu * mu;
    if (var < 0) var = 0;
    double sc = (double)gb[c] / sqrt(var + 1e-5);
    double sh = (double)gb[16 + c] - mu * sc;
    stD[c] = sc; stD[16 + c] = sh;
    stF[c] = (float)sc; stF[16 + c] = (float)sh;
  }
}

// ---- conv1 tiled: 64x4 tile, all 16 co per block, x staged once in LDS ----
__global__ __launch_bounds__(256) void conv1_t(const void* __restrict__ x, const float* __restrict__ PF,
                                               float* __restrict__ y, D2* __restrict__ part,
                                               const int* modep) {
  const int m = *modep;
  __shared__ float sx[10 * 130];
  int t = threadIdx.x;
  int bx = blockIdx.x;
  int b = bx >> 8, r = bx & 255, tY = r >> 2, tX = r & 3;   // 64 tY x 4 tX tiles of 64x4
  int iy0 = 8 * tY - 1, ix0 = 128 * tX - 1;
  size_t xb = (size_t)b * 262144;
  for (int i = t; i < 1300; i += 256) {
    int ry = i / 130, rx = i - ry * 130;
    int gy = iy0 + ry, gx = ix0 + rx;
    float v = 0.f;
    if ((unsigned)gy < 512u && (unsigned)gx < 512u) v = ldv(x, xb + (size_t)gy * 512 + gx, m);
    sx[i] = v;
  }
  __syncthreads();
  int tyy = t >> 6, txx = t & 63;
  int oy = tY * 4 + tyy, ox = tX * 64 + txx;
  float acc[16];
#pragma unroll
  for (int co = 0; co < 16; co++) acc[co] = PF[256 + co];
  int ly = 2 * tyy, lx = 2 * txx;
#pragma unroll
  for (int ky = 0; ky < 4; ky++) {
#pragma unroll
    for (int kx = 0; kx < 4; kx++) {
      float v = sx[(ly + ky) * 130 + lx + kx];
#pragma unroll
      for (int co = 0; co < 16; co++) acc[co] = fmaf(v, PF[co * 16 + ky * 4 + kx], acc[co]);
    }
  }
  int rem = oy * 256 + ox;
  float vq_[16];
#pragma unroll
  for (int co = 0; co < 16; co++) {
    y[((size_t)(b * 16 + co) << 16) + rem] = acc[co];
    vq_[co] = acc[co] * acc[co];
  }
  block_stats16(acc, vq_, part, 8192, bx);
}

// ---- conv2 tiled: all 16 co per block, 16x16 tile, LDS staged per-ci ----
__global__ __launch_bounds__(256) void conv2_t(const float* __restrict__ h1, const float* __restrict__ PF,
                                               const float* __restrict__ aff, float* __restrict__ h2,
                                               D2* __restrict__ part) {
  __shared__ float su[34 * 34];
  int t = threadIdx.x, ty = t >> 4, tx = t & 15;
  int bx = blockIdx.x, bb = bx >> 6, r = bx & 63, tY = r >> 3, tX = r & 7;
  int oy = tY * 16 + ty, ox = tX * 16 + tx;
  int iy0 = 32 * tY - 1, ix0 = 32 * tX - 1;
  const float* W2 = PF + 272;
  float acc[16];
#pragma unroll
  for (int co = 0; co < 16; co++) acc[co] = PF[4368 + co];
  for (int ci = 0; ci < 16; ci++) {
    __syncthreads();
    float sc = aff[ci], sh = aff[16 + ci];
    const float* ib = h1 + ((size_t)(bb * 16 + ci) << 16);
    for (int i = t; i < 1156; i += 256) {
      int riy = i / 34, rix = i - riy * 34;
      int gy = iy0 + riy, gx = ix0 + rix;
      float v = 0.f;
      if ((unsigned)gy < 256u && (unsigned)gx < 256u) v = fmaxf(fmaf(ib[gy * 256 + gx], sc, sh), 0.f);
      su[i] = v;
    }
    __syncthreads();
    const float* wci = W2 + ci * 16;
#pragma unroll
    for (int ky = 0; ky < 4; ky++) {
#pragma unroll
      for (int kx = 0; kx < 4; kx++) {
        float v = su[(2 * ty + ky) * 34 + 2 * tx + kx];
        const float* wt = wci + ky * 4 + kx;
#pragma unroll
        for (int co = 0; co < 16; co++) acc[co] = fmaf(v, wt[co * 256], acc[co]);
      }
    }
  }
  float vq_[16];
#pragma unroll
  for (int co = 0; co < 16; co++) {
    h2[((size_t)(bb * 16 + co) * 128 + oy) * 128 + ox] = acc[co];
    vq_[co] = acc[co] * acc[co];
  }
  block_stats16(acc, vq_, part, 2048, bx);
}

// ---- conv3: f32 h2 (affine2+relu) -> f64 raw conv out (32,4,64,64) ----
__global__ __launch_bounds__(256) void conv3_k(const float* __restrict__ h2, const double* __restrict__ PD,
                                               const float* __restrict__ aff, double* __restrict__ c3,
                                               D2* __restrict__ part) {
  const int co = blockIdx.y;
  int idx = blockIdx.x * 256 + threadIdx.x;   // 131072
  int b = idx >> 12, rem = idx & 4095, oy = rem >> 6, ox = rem & 63;
  double acc = PD[1024 + co];
  int iy0 = 2 * oy - 1, ix0 = 2 * ox - 1;
  for (int ci = 0; ci < 16; ci++) {
    const float* ib = h2 + (size_t)(b * 16 + ci) * 16384;
    float sc = aff[ci], sh = aff[16 + ci];
    const double* wr = PD + co * 256 + ci * 16;
#pragma unroll
    for (int ky = 0; ky < 4; ky++) {
      int iy = iy0 + ky;
      if ((unsigned)iy < 128u) {
        const float* row = ib + iy * 128;
#pragma unroll
        for (int kx = 0; kx < 4; kx++) {
          int ix = ix0 + kx;
          if ((unsigned)ix < 128u) {
            float v = fmaxf(fmaf(row[ix], sc, sh), 0.f);
            acc = fma((double)v, wr[ky * 4 + kx], acc);
          }
        }
      }
    }
  }
  c3[(size_t)(b * 4 + co) * 4096 + rem] = acc;
  block_stats1d(acc, acc * acc, part + (co * 512 + blockIdx.x));
}

// ---- VQ: f64 BN3 affine+relu -> wpre -> argmin -> wpost -> d0 (f32) ----
__global__ __launch_bounds__(256) void vq_k(const double* __restrict__ c3, const double* __restrict__ PD,
                                            const double* __restrict__ stD2, float* __restrict__ d0,
                                            double* __restrict__ vp) {
  __shared__ double cb[512];
  for (int i = threadIdx.x; i < 512; i += 256) cb[i] = PD[1040 + i];
  __syncthreads();
  int pix = blockIdx.x * 256 + threadIdx.x;
  int b = pix >> 12, rem = pix & 4095;
  const double* hb = c3 + (size_t)b * 16384 + rem;
  double q0 = PD[1036], q1 = PD[1037];
#pragma unroll
  for (int ci = 0; ci < 4; ci++) {
    double v = fma(hb[ci * 4096], stD2[ci], stD2[16 + ci]);
    if (v < 0) v = 0;
    q0 = fma(v, PD[1028 + ci], q0);
    q1 = fma(v, PD[1032 + ci], q1);
  }
  int best = 0;
  double bd = 1e300;
  for (int k = 0; k < 256; k++) {
    double dx = q0 - cb[2 * k], dy = q1 - cb[2 * k + 1];
    double d = dx * dx + dy * dy;
    if (d < bd) { bd = d; best = k; }   // strict < == first-index argmin
  }
  double c0 = cb[2 * best], c1 = cb[2 * best + 1];
  double e0 = q0 - c0, e1 = q1 - c1;
  float* ob = d0 + (size_t)b * 16384 + rem;
#pragma unroll
  for (int c = 0; c < 4; c++)
    ob[c * 4096] = (float)(PD[1560 + c] + PD[1552 + 2 * c] * c0 + PD[1552 + 2 * c + 1] * c1);
  double v = e0 * e0 + e1 * e1;
#pragma unroll
  for (int o = 32; o; o >>= 1) v += __shfl_down(v, o, 64);
  __shared__ double l1[4];
  int lane = threadIdx.x & 63, w = threadIdx.x >> 6;
  if (lane == 0) l1[w] = v;
  __syncthreads();
  if (threadIdx.x == 0) vp[blockIdx.x] = l1[0] + l1[1] + l1[2] + l1[3];
}

// ---- deconv1: d0 (32,4,64,64) -> d1 raw (32,16,128,128), per-px ----
__global__ __launch_bounds__(256) void deconv1_k(const float* __restrict__ d0, const float* __restrict__ PF,
                                                 float* __restrict__ d1, D2* __restrict__ part) {
  const int co = blockIdx.y;
  __shared__ float wl[64];
  if (threadIdx.x < 64) wl[threadIdx.x] = PF[4384 + co * 64 + threadIdx.x];
  __syncthreads();
  int idx = blockIdx.x * 256 + threadIdx.x;   // 524288
  int b = idx >> 14, rem = idx & 16383, oy = rem >> 7, ox = rem & 127;
  float acc = PF[5408 + co];
  int ry = (oy + 1) & 1, rx = (ox + 1) & 1;
#pragma unroll
  for (int ci = 0; ci < 4; ci++) {
    const float* ib = d0 + (size_t)(b * 4 + ci) * 4096;
    const float* wr = wl + ci * 16;
#pragma unroll
    for (int t2y = 0; t2y < 2; t2y++) {
      int ky = ry + 2 * t2y, iy = (oy + 1 - ky) >> 1;
      if ((unsigned)iy < 64u) {
#pragma unroll
        for (int t2x = 0; t2x < 2; t2x++) {
          int kx = rx + 2 * t2x, ix = (ox + 1 - kx) >> 1;
          if ((unsigned)ix < 64u) acc = fmaf(ib[iy * 64 + ix], wr[ky * 4 + kx], acc);
        }
      }
    }
  }
  d1[(size_t)(b * 16 + co) * 16384 + rem] = acc;
  block_stats1(acc, part + (co * 2048 + blockIdx.x));
}

// ---- deconv2 tiled: 2x2 quad per thread, 32x32 tile, all 16 co ----
__global__ __launch_bounds__(256) void deconv2_t(const float* __restrict__ d1, const float* __restrict__ PF,
                                                 const float* __restrict__ aff, float* __restrict__ d2,
                                                 D2* __restrict__ part) {
  __shared__ float su[16 * 324];
  int t = threadIdx.x, qy = t >> 4, qx = t & 15;
  int bx = blockIdx.x, bb = bx >> 6, r = bx & 63, tY = r >> 3, tX = r & 7;
  int oy0 = 32 * tY, ox0 = 32 * tX;
  int iy0 = 16 * tY - 1, ix0 = 16 * tX - 1;
  for (int i = t; i < 5184; i += 256) {
    int ci = i / 324, rr = i - ci * 324;
    int riy = rr / 18, rix = rr - riy * 18;
    int gy = iy0 + riy, gx = ix0 + rix;
    float v = 0.f;
    if ((unsigned)gy < 128u && (unsigned)gx < 128u)
      v = fmaxf(fmaf(d1[(size_t)(bb * 16 + ci) * 16384 + gy * 128 + gx], aff[ci], aff[16 + ci]), 0.f);
    su[i] = v;
  }
  __syncthreads();
  const float* WD2 = PF + 5424;
  float acc[4][16];
#pragma unroll
  for (int p = 0; p < 4; p++)
#pragma unroll
    for (int co = 0; co < 16; co++) acc[p][co] = PF[9520 + co];
  for (int ci = 0; ci < 16; ci++) {
    float sv[3][3];
#pragma unroll
    for (int dy = 0; dy < 3; dy++)
#pragma unroll
      for (int dx = 0; dx < 3; dx++) sv[dy][dx] = su[ci * 324 + (qy + dy) * 18 + (qx + dx)];
    const float* wci = WD2 + ci * 16;
#pragma unroll
    for (int a = 0; a < 2; a++)
#pragma unroll
      for (int bc = 0; bc < 2; bc++) {
        int p = a * 2 + bc;
#pragma unroll
        for (int t2y = 0; t2y < 2; t2y++) {
          int ky = 1 - a + 2 * t2y, dy = 1 + a - t2y;
#pragma unroll
          for (int t2x = 0; t2x < 2; t2x++) {
            int kx = 1 - bc + 2 * t2x, dx = 1 + bc - t2x;
            float v = sv[dy][dx];
            const float* wt = wci + ky * 4 + kx;
#pragma unroll
            for (int co = 0; co < 16; co++) acc[p][co] = fmaf(v, wt[co * 256], acc[p][co]);
          }
        }
      }
  }
#pragma unroll
  for (int a = 0; a < 2; a++)
#pragma unroll
    for (int bc = 0; bc < 2; bc++) {
      int oy = oy0 + 2 * qy + a, ox = ox0 + 2 * qx + bc, p = a * 2 + bc;
#pragma unroll
      for (int co = 0; co < 16; co++)
        d2[((size_t)(bb * 16 + co) * 256 + oy) * 256 + ox] = acc[p][co];
    }
  float vs[16], vqq[16];
#pragma unroll
  for (int co = 0; co < 16; co++) {
    vs[co]  = acc[0][co] + acc[1][co] + acc[2][co] + acc[3][co];
    vqq[co] = acc[0][co] * acc[0][co] + acc[1][co] * acc[1][co] +
              acc[2][co] * acc[2][co] + acc[3][co] * acc[3][co];
  }
  block_stats16(vs, vqq, part, 2048, bx);
}

// ---- deconv3 tiled: 32x32 out tile, d2 staged (affine+relu applied),
// ---- 1x4 strip per thread, sigmoid + store + MSE partial ----
__global__ __launch_bounds__(256) void deconv3_t(const float* __restrict__ d2, const float* __restrict__ PF,
                                                 const float* __restrict__ aff, const void* __restrict__ x,
                                                 void* __restrict__ outp, double* __restrict__ rp,
                                                 const int* modep) {
  const int m = *modep;
  __shared__ float sd[16 * 324];
  __shared__ float wl[256];
  int t = threadIdx.x;
  wl[t] = PF[9536 + t];
  int bx = blockIdx.x;
  int b = bx >> 8, r = bx & 255, tY = r >> 4, tX = r & 15;   // 16x16 tiles of 32x32
  int oy0 = 32 * tY, ox0 = 32 * tX;
  int iy0 = 16 * tY - 1, ix0 = 16 * tX - 1;
  for (int i = t; i < 5184; i += 256) {
    int ci = i / 324, rr = i - ci * 324;
    int ry = rr / 18, rx = rr - ry * 18;
    int gy = iy0 + ry, gx = ix0 + rx;
    float v = 0.f;
    if ((unsigned)gy < 256u && (unsigned)gx < 256u)
      v = fmaxf(fmaf(d2[(size_t)(b * 16 + ci) * 65536 + gy * 256 + gx], aff[ci], aff[16 + ci]), 0.f);
    sd[i] = v;
  }
  __syncthreads();
  int qy = t >> 3, qx = t & 7;     // row 0..31, col-group 0..7 (4 cols)
  int oy = oy0 + qy;
  int ry = (oy + 1) & 1;
  float acc[4];
#pragma unroll
  for (int c = 0; c < 4; c++) acc[c] = PF[9792];
  for (int ci = 0; ci < 16; ci++) {
    const float* sc_ = sd + ci * 324;
    const float* wr = wl + ci * 16;
#pragma unroll
    for (int t2y = 0; t2y < 2; t2y++) {
      int ky = ry + 2 * t2y;
      int iy = (oy + 1 - ky) >> 1;
      int liy = iy - iy0;
#pragma unroll
      for (int c = 0; c < 4; c++) {
        int oxc = ox0 + 4 * qx + c;
        int kxp = (c + 1) & 1;
#pragma unroll
        for (int t2x = 0; t2x < 2; t2x++) {
          int kx = kxp + 2 * t2x;
          int lix = ((oxc + 1 - kx) >> 1) - ix0;
          acc[c] = fmaf(sc_[liy * 18 + lix], wr[ky * 4 + kx], acc[c]);
        }
      }
    }
  }
  size_t obase = (size_t)b * 262144 + (size_t)oy * 512 + ox0 + 4 * qx;
  float ds = 0.f;
#pragma unroll
  for (int c = 0; c < 4; c++) {
    float o = 1.f / (1.f + expf(-acc[c]));
    if (m) ((bf16*)outp)[obase + c] = __float2bfloat16(o);
    else   ((float*)outp)[obase + c] = o;
    float dd = ldv(x, obase + c, m) - o;
    ds = fmaf(dd, dd, ds);
  }
  block_sum1(ds, rp + bx);
}

__global__ __launch_bounds__(256) void finalize_k(const double* __restrict__ vp, const double* __restrict__ rp,
                                                  void* outp, const int* modep) {
  double s = 0, rr = 0;
  for (int i = threadIdx.x; i < 512; i += 256) s += vp[i];
  for (int i = threadIdx.x; i < 8192; i += 256) rr += rp[i];
#pragma unroll
  for (int o = 32; o; o >>= 1) { s += __shfl_down(s, o, 64); rr += __shfl_down(rr, o, 64); }
  __shared__ double l1[4], l2[4];
  int lane = threadIdx.x & 63, w = threadIdx.x >> 6;
  if (lane == 0) { l1[w] = s; l2[w] = rr; }
  __syncthreads();
  if (threadIdx.x == 0) {
    double S = l1[0] + l1[1] + l1[2] + l1[3], R = l2[0] + l2[1] + l2[2] + l2[3];
    double total = R * (1.0 / 8388608.0) + 1.2 * (S * (1.0 / 262144.0));
    if (*modep) ((bf16*)outp)[8388608] = __float2bfloat16((float)total);
    else        ((float*)outp)[8388608] = (float)total;
  }
}

extern "C" void kernel_launch(void* const* d_in, const int* in_sizes, int n_in,
                              void* d_out, int out_size, void* d_ws, size_t ws_size,
                              hipStream_t stream) {
  const void* x    = d_in[0];
  const void* w1   = d_in[1];  const void* b1  = d_in[2];
  const void* g1   = d_in[3];  const void* be1 = d_in[4];
  const void* w2   = d_in[5];  const void* b2  = d_in[6];
  const void* g2   = d_in[7];  const void* be2 = d_in[8];
  const void* w3   = d_in[9];  const void* b3  = d_in[10];
  const void* g3   = d_in[11]; const void* be3 = d_in[12];
  const void* wpre = d_in[13]; const void* bpre= d_in[14];
  const void* cbk  = d_in[15];
  const void* wpost= d_in[16]; const void* bpost= d_in[17];
  const void* wd1  = d_in[18]; const void* bd1 = d_in[19];
  const void* g4   = d_in[20]; const void* be4 = d_in[21];
  const void* wd2  = d_in[22]; const void* bd2 = d_in[23];
  const void* g5   = d_in[24]; const void* be5 = d_in[25];
  const void* wd3  = d_in[26]; const void* bd3 = d_in[27];

  char* ws = (char*)d_ws;
  int*    MODE = (int*)ws;
  float*  STF  = (float*)(ws + 1024);      // 5 layers x 32 f
  double* STD  = (double*)(ws + 4096);     // 5 layers x 32 d
  float*  PF   = (float*)(ws + 8192);
  double* PD   = (double*)(ws + 73728);
  D2*     P1   = (D2*)(ws + 131072);       // 16*8192
  D2*     P2   = (D2*)(ws + 2228224);      // 16*2048
  D2*     P3   = (D2*)(ws + 2752512);      // 4*512
  D2*     P4   = (D2*)(ws + 2785280);      // 16*2048
  D2*     P5   = (D2*)(ws + 3309568);      // 16*2048
  double* VP   = (double*)(ws + 3833856);  // 512
  double* RP   = (double*)(ws + 3837952);  // 8192
  char* HB = ws + 6291456;
  float*  H1  = (float*)HB;                       // 134 MB
  float*  H2  = (float*)(HB + 134217728);         // 33.5 MB
  double* C3  = (double*)HB;                      // 4 MB, reuses dead H1
  float*  D0  = (float*)(HB + 165675008);         // 2 MB, inside dead H2
  float*  D1  = (float*)HB;                       // reuses dead C3
  float*  D2T = (float*)(HB + 33554432);          // 134 MB, overwrites dead H2/D0

  init_k<<<1, 256, 0, stream>>>((const unsigned*)x, MODE);
  prep_k<<<1, 256, 0, stream>>>(w1, b1, w2, b2, w3, b3, wpre, bpre, cbk, wpost, bpost,
                                wd1, bd1, wd2, bd2, wd3, bd3,
                                g1, be1, g2, be2, g3, be3, g4, be4, g5, be5, PF, PD, MODE);

  conv1_t<<<8192, 256, 0, stream>>>(x, PF, H1, P1, MODE);
  bn_reduce_k<<<16, 256, 0, stream>>>(P1, 8192, STD + 0, STF + 0, PF + 9856, 1.0 / 2097152.0);

  conv2_t<<<2048, 256, 0, stream>>>(H1, PF, STF + 0, H2, P2);
  bn_reduce_k<<<16, 256, 0, stream>>>(P2, 2048, STD + 32, STF + 32, PF + 9888, 1.0 / 524288.0);

  conv3_k<<<dim3(512, 4), 256, 0, stream>>>(H2, PD, STF + 32, C3, P3);
  bn_reduce_k<<<4, 256, 0, stream>>>(P3, 512, STD + 64, STF + 64, PF + 9920, 1.0 / 131072.0);

  vq_k<<<512, 256, 0, stream>>>(C3, PD, STD + 64, D0, VP);

  deconv1_k<<<dim3(2048, 16), 256, 0, stream>>>(D0, PF, D1, P4);
  bn_reduce_k<<<16, 256, 0, stream>>>(P4, 2048, STD + 96, STF + 96, PF + 9952, 1.0 / 524288.0);

  deconv2_t<<<2048, 256, 0, stream>>>(D1, PF, STF + 96, D2T, P5);
  bn_reduce_k<<<16, 256, 0, stream>>>(P5, 2048, STD + 128, STF + 128, PF + 9984, 1.0 / 2097152.0);

  deconv3_t<<<8192, 256, 0, stream>>>(D2T, PF, STF + 128, x, d_out, RP, MODE);
  finalize_k<<<1, 256, 0, stream>>>(VP, RP, d_out, MODE);
}